// Round 12
// baseline (589.721 us; speedup 1.0000x reference)
//
#include <hip/hip_runtime.h>

#define NU 50000
#define NI 100000
#define NT 150000
#define NTP 150528   // NT padded to 147*1024 (pad nodes have deg 0)
#define BB 4096
#define KLB 1920     // KL blocks

typedef __attribute__((ext_vector_type(8))) short bf16x8;
typedef __attribute__((ext_vector_type(4))) float f32x4;
typedef __attribute__((ext_vector_type(2))) float f32x2;
typedef unsigned long long u64;

__device__ __forceinline__ float softplusf(float x) {
  return fmaxf(x, 0.f) + __logf(1.f + __expf(-fabsf(x)));
}
__device__ __forceinline__ float wsum(float v) {
#pragma unroll
  for (int o = 32; o > 0; o >>= 1) v += __shfl_xor(v, o, 64);
  return v;
}
__device__ __forceinline__ unsigned short f2b(float x) {
  unsigned u = __float_as_uint(x);
  return (unsigned short)((u + 0x7FFFu + ((u >> 16) & 1u)) >> 16);
}
__device__ __forceinline__ float b2f(unsigned us) {  // low 16 bits = bf16
  return __uint_as_float(us << 16);
}
__device__ __forceinline__ float bfe(bf16x8 v, int j) {  // frag elem -> f32
  return __uint_as_float(((unsigned)(unsigned short)v[j]) << 16);
}
__device__ __forceinline__ void unp4(u64 v, float* o) {
  unsigned lo = (unsigned)v, hi = (unsigned)(v >> 32);
  o[0] = __uint_as_float(lo << 16);
  o[1] = __uint_as_float(lo & 0xffff0000u);
  o[2] = __uint_as_float(hi << 16);
  o[3] = __uint_as_float(hi & 0xffff0000u);
}
__device__ __forceinline__ u64 pk4(float x0, float x1, float x2, float x3) {
  return (u64)((unsigned)f2b(x0) | ((unsigned)f2b(x1) << 16)) |
         ((u64)((unsigned)f2b(x2) | ((unsigned)f2b(x3) << 16)) << 32);
}
// real packed dual-FMA (VOP3P) — compiler scalarizes float2 '+=', force it.
__device__ __forceinline__ f32x2 pkfma(f32x2 a, f32x2 b, f32x2 c) {
  f32x2 d;
  asm("v_pk_fma_f32 %0, %1, %2, %3" : "=v"(d) : "v"(a), "v"(b), "v"(c));
  return d;
}

// ---------------- CSR build (round 24: direct global-atomic build) ----------
// Old bucket design made 4 passes over edge data (part scatter + count2 read
// + fill2 read/write, ~80-90us). Global atomics over 150K addresses (~21
// hits each, random -> all L2 channels) cost only ~5-10us for 3.15M ops,
// and edges[] (25MB) is L2-resident so scattered 8B stores write-combine.
__global__ __launch_bounds__(256) void k_deg(const int* __restrict__ h,
                                             int* __restrict__ deg, int E) {
  int i0 = (blockIdx.x * 256 + threadIdx.x) * 4;
  if (i0 + 3 < E) {
    int4 v = *(const int4*)(h + i0);
    atomicAdd(&deg[v.x], 1);
    atomicAdd(&deg[v.y], 1);
    atomicAdd(&deg[v.z], 1);
    atomicAdd(&deg[v.w], 1);
  } else {
    for (int j = i0; j < E; j++) atomicAdd(&deg[h[j]], 1);
  }
}

// 147 blocks; block b scans its 1024 degrees -> local offsets + bucket total
__global__ __launch_bounds__(256) void k_scan1(const int* __restrict__ deg,
                                               int* __restrict__ rloc_g,
                                               float* __restrict__ d_inv,
                                               int* __restrict__ btot) {
  __shared__ int sd[256];
  int b = blockIdx.x, tid = threadIdx.x;
  int n0 = b << 10;
  int4 dv = ((const int4*)(deg + n0))[tid];
  int pd[4] = {dv.x, dv.y, dv.z, dv.w};
  int s = pd[0] + pd[1] + pd[2] + pd[3];
#pragma unroll
  for (int j = 0; j < 4; j++) {
    int n = n0 + tid * 4 + j;
    if (n < NT) d_inv[n] = 1.0f / sqrtf((float)pd[j]);  // deg >= 1 (self-loop)
  }
  sd[tid] = s;
  __syncthreads();
  for (int o = 1; o < 256; o <<= 1) {
    int x = (tid >= o) ? sd[tid - o] : 0;
    __syncthreads();
    sd[tid] += x;
    __syncthreads();
  }
  int run2 = sd[tid] - s;
#pragma unroll
  for (int j = 0; j < 4; j++) {
    rloc_g[n0 + tid * 4 + j] = run2;
    run2 += pd[j];
  }
  if (tid == 255) btot[b] = sd[255];
}

// 586 blocks; redundant 147-entry scan of btot, write row_ptr + cursor
__global__ __launch_bounds__(256) void k_scan2(const int* __restrict__ btot,
                                               const int* __restrict__ rloc_g,
                                               int* __restrict__ row_ptr,
                                               int* __restrict__ cursor) {
  __shared__ int sd[256];
  __shared__ int exs[256];
  int t = threadIdx.x;
  int v = (t < 147) ? btot[t] : 0;
  sd[t] = v;
  __syncthreads();
  for (int o = 1; o < 256; o <<= 1) {
    int x = (t >= o) ? sd[t - o] : 0;
    __syncthreads();
    sd[t] += x;
    __syncthreads();
  }
  exs[t] = sd[t] - v;
  __syncthreads();
  int n = blockIdx.x * 256 + t;
  if (n < NT) {
    int rp = exs[n >> 10] + rloc_g[n];
    row_ptr[n] = rp;
    cursor[n] = rp;
  }
  if (blockIdx.x == 0 && t == 0) row_ptr[NT] = sd[146];
}

__global__ __launch_bounds__(256) void k_place(const int* __restrict__ h,
                                               const int* __restrict__ t,
                                               int* __restrict__ cursor,
                                               const float* __restrict__ d_inv,
                                               uint2* __restrict__ edges, int E) {
  int i0 = (blockIdx.x * 256 + threadIdx.x) * 4;
  if (i0 + 3 < E) {
    int4 hv = *(const int4*)(h + i0);
    int4 tv = *(const int4*)(t + i0);
#pragma unroll
    for (int j = 0; j < 4; j++) {
      int hh = (j == 0) ? hv.x : (j == 1) ? hv.y : (j == 2) ? hv.z : hv.w;
      int tt = (j == 0) ? tv.x : (j == 1) ? tv.y : (j == 2) ? tv.z : tv.w;
      int slot = atomicAdd(&cursor[hh], 1);
      float g = d_inv[hh] * d_inv[tt];
      uint2 w; w.x = (unsigned)tt; w.y = __float_as_uint(g);
      edges[slot] = w;
    }
  } else {
    for (int j = i0; j < E; j++) {
      int hh = h[j], tt = t[j];
      int slot = atomicAdd(&cursor[hh], 1);
      float g = d_inv[hh] * d_inv[tt];
      uint2 w; w.x = (unsigned)tt; w.y = __float_as_uint(g);
      edges[slot] = w;
    }
  }
}

// ---------------- propagation ----------------
__global__ void k_init(const float4* __restrict__ ue, const float4* __restrict__ ie,
                       unsigned* __restrict__ cur, u64* __restrict__ acc64,
                       int nU4, int nTot4) {
  int i = blockIdx.x * 256 + threadIdx.x;
  if (i >= nTot4) return;
  float4 v = (i < nU4) ? ue[i] : ie[i - nU4];
  int p = __builtin_amdgcn_cvt_pk_fp8_f32(v.x, v.y, 0, false);
  p = __builtin_amdgcn_cvt_pk_fp8_f32(v.z, v.w, p, true);
  cur[i] = (unsigned)p;
  acc64[i] = pk4(v.x, v.y, v.z, v.w);
}

// 32-edge step for one node: 2 record loads + 8 gathers + 16 cvt + 16 pk_fma.
__device__ __forceinline__ void agg32(const u64* __restrict__ ep,
                                      const unsigned* __restrict__ cur,
                                      int i, int e, int d, int b4,
                                      f32x2& a01, f32x2& a23) {
  int ia = i + d;
  int ib = ia + 16;
  u64 ra = ep[ia < e ? ia : e - 1];
  u64 rb = ep[ib < e ? ib : e - 1];
  unsigned rax = (unsigned)ra;
  unsigned ray = (ia < e) ? (unsigned)(ra >> 32) : 0u;
  unsigned rbx = (unsigned)rb;
  unsigned rby = (ib < e) ? (unsigned)(rb >> 32) : 0u;
  unsigned iA0 = __shfl(rax, b4 + 0, 64); float gA0 = __uint_as_float(__shfl(ray, b4 + 0, 64));
  unsigned iA1 = __shfl(rax, b4 + 1, 64); float gA1 = __uint_as_float(__shfl(ray, b4 + 1, 64));
  unsigned iA2 = __shfl(rax, b4 + 2, 64); float gA2 = __uint_as_float(__shfl(ray, b4 + 2, 64));
  unsigned iA3 = __shfl(rax, b4 + 3, 64); float gA3 = __uint_as_float(__shfl(ray, b4 + 3, 64));
  unsigned vA0 = cur[(iA0 << 4) + (unsigned)d];
  unsigned vA1 = cur[(iA1 << 4) + (unsigned)d];
  unsigned vA2 = cur[(iA2 << 4) + (unsigned)d];
  unsigned vA3 = cur[(iA3 << 4) + (unsigned)d];
  unsigned iB0 = __shfl(rbx, b4 + 0, 64); float gB0 = __uint_as_float(__shfl(rby, b4 + 0, 64));
  unsigned iB1 = __shfl(rbx, b4 + 1, 64); float gB1 = __uint_as_float(__shfl(rby, b4 + 1, 64));
  unsigned iB2 = __shfl(rbx, b4 + 2, 64); float gB2 = __uint_as_float(__shfl(rby, b4 + 2, 64));
  unsigned iB3 = __shfl(rbx, b4 + 3, 64); float gB3 = __uint_as_float(__shfl(rby, b4 + 3, 64));
  unsigned vB0 = cur[(iB0 << 4) + (unsigned)d];
  unsigned vB1 = cur[(iB1 << 4) + (unsigned)d];
  unsigned vB2 = cur[(iB2 << 4) + (unsigned)d];
  unsigned vB3 = cur[(iB3 << 4) + (unsigned)d];
  f32x2 g2;
  g2.x = gA0; g2.y = gA0;
  a01 = pkfma(__builtin_amdgcn_cvt_pk_f32_fp8(vA0, false), g2, a01);
  a23 = pkfma(__builtin_amdgcn_cvt_pk_f32_fp8(vA0, true), g2, a23);
  g2.x = gA1; g2.y = gA1;
  a01 = pkfma(__builtin_amdgcn_cvt_pk_f32_fp8(vA1, false), g2, a01);
  a23 = pkfma(__builtin_amdgcn_cvt_pk_f32_fp8(vA1, true), g2, a23);
  g2.x = gA2; g2.y = gA2;
  a01 = pkfma(__builtin_amdgcn_cvt_pk_f32_fp8(vA2, false), g2, a01);
  a23 = pkfma(__builtin_amdgcn_cvt_pk_f32_fp8(vA2, true), g2, a23);
  g2.x = gA3; g2.y = gA3;
  a01 = pkfma(__builtin_amdgcn_cvt_pk_f32_fp8(vA3, false), g2, a01);
  a23 = pkfma(__builtin_amdgcn_cvt_pk_f32_fp8(vA3, true), g2, a23);
  g2.x = gB0; g2.y = gB0;
  a01 = pkfma(__builtin_amdgcn_cvt_pk_f32_fp8(vB0, false), g2, a01);
  a23 = pkfma(__builtin_amdgcn_cvt_pk_f32_fp8(vB0, true), g2, a23);
  g2.x = gB1; g2.y = gB1;
  a01 = pkfma(__builtin_amdgcn_cvt_pk_f32_fp8(vB1, false), g2, a01);
  a23 = pkfma(__builtin_amdgcn_cvt_pk_f32_fp8(vB1, true), g2, a23);
  g2.x = gB2; g2.y = gB2;
  a01 = pkfma(__builtin_amdgcn_cvt_pk_f32_fp8(vB2, false), g2, a01);
  a23 = pkfma(__builtin_amdgcn_cvt_pk_f32_fp8(vB2, true), g2, a23);
  g2.x = gB3; g2.y = gB3;
  a01 = pkfma(__builtin_amdgcn_cvt_pk_f32_fp8(vB3, false), g2, a01);
  a23 = pkfma(__builtin_amdgcn_cvt_pk_f32_fp8(vB3, true), g2, a23);
}

// TWO adjacent nodes per wave (grid NT/8); epilogue uses all 4 quarter-groups.
// Round 24: uniform-branch skip for unequal pair lengths (scalar branch on
// wave-uniform bounds) — avoids ~15% wasted clamped iterations.
// NOTE: flat named registers only — register ARRAYS here spill (round 7).
__global__ __launch_bounds__(256) void k_agg(const int* __restrict__ row_ptr,
                                             const uint2* __restrict__ edges,
                                             const unsigned* __restrict__ cur,
                                             unsigned* __restrict__ nxt,
                                             u64* __restrict__ acc64,
                                             int last) {
  int node0 = (((blockIdx.x << 2) + (threadIdx.x >> 6)) << 1);
  int node1 = node0 + 1;
  unsigned lane = threadIdx.x & 63;
  int d = (int)(lane & 15);
  int g = (int)(lane >> 4);
  int b4 = g << 2;
  int s0 = row_ptr[node0];
  int e0 = row_ptr[node1];      // == s1
  int e1 = row_ptr[node1 + 1];
  int s1 = e0;
  f32x2 x01 = {0.f, 0.f}, x23 = {0.f, 0.f};
  f32x2 y01 = {0.f, 0.f}, y23 = {0.f, 0.f};
  const u64* ep = (const u64*)edges;
  int l0 = e0 - s0, l1 = e1 - s1;
  int len = l0 > l1 ? l0 : l1;
  for (int k = 0; k < len; k += 32) {
    if (k < l0) agg32(ep, cur, s0 + k, e0, d, b4, x01, x23);
    if (k < l1) agg32(ep, cur, s1 + k, e1, d, b4, y01, y23);
  }
  float x0 = x01.x, x1 = x01.y, x2 = x23.x, x3 = x23.y;
  float y0 = y01.x, y1 = y01.y, y2 = y23.x, y3 = y23.y;
  x0 += __shfl_xor(x0, 16, 64); x1 += __shfl_xor(x1, 16, 64);
  x2 += __shfl_xor(x2, 16, 64); x3 += __shfl_xor(x3, 16, 64);
  y0 += __shfl_xor(y0, 16, 64); y1 += __shfl_xor(y1, 16, 64);
  y2 += __shfl_xor(y2, 16, 64); y3 += __shfl_xor(y3, 16, 64);
  x0 += __shfl_xor(x0, 32, 64); x1 += __shfl_xor(x1, 32, 64);
  x2 += __shfl_xor(x2, 32, 64); x3 += __shfl_xor(x3, 32, 64);
  y0 += __shfl_xor(y0, 32, 64); y1 += __shfl_xor(y1, 32, 64);
  y2 += __shfl_xor(y2, 32, 64); y3 += __shfl_xor(y3, 32, 64);
  if (g < 2) {
    int nd = (g == 0) ? node0 : node1;
    float a0 = (g == 0) ? x0 : y0;
    float a1 = (g == 0) ? x1 : y1;
    float a2 = (g == 0) ? x2 : y2;
    float a3 = (g == 0) ? x3 : y3;
    unsigned ro = ((unsigned)nd << 4) + (unsigned)d;
    u64 pv = acc64[ro];
    unsigned lo32 = (unsigned)pv, hi32 = (unsigned)(pv >> 32);
    float z0 = __uint_as_float(lo32 << 16) + a0;
    float z1 = __uint_as_float(lo32 & 0xffff0000u) + a1;
    float z2 = __uint_as_float(hi32 << 16) + a2;
    float z3 = __uint_as_float(hi32 & 0xffff0000u) + a3;
    acc64[ro] = pk4(z0, z1, z2, z3);
  } else if (!last) {
    int nd = (g == 2) ? node0 : node1;
    float a0 = (g == 2) ? x0 : y0;
    float a1 = (g == 2) ? x1 : y1;
    float a2 = (g == 2) ? x2 : y2;
    float a3 = (g == 2) ? x3 : y3;
    unsigned ro = ((unsigned)nd << 4) + (unsigned)d;
    int p = __builtin_amdgcn_cvt_pk_fp8_f32(a0, a1, 0, false);
    p = __builtin_amdgcn_cvt_pk_fp8_f32(a2, a3, p, true);
    nxt[ro] = (unsigned)p;
  }
}

// ---------------- batch pass (MFMA, 128 blocks, big LDS) ----------------
__global__ __launch_bounds__(256) void k_batch(
    const unsigned short* __restrict__ accB,
    const float* __restrict__ user_emb, const float* __restrict__ item_emb,
    const float* __restrict__ eps,
    const float* __restrict__ user_int, const float* __restrict__ item_int,
    const float* __restrict__ lin_w, const float* __restrict__ lin_b,
    const int* __restrict__ users, const int* __restrict__ pos_items,
    const int* __restrict__ neg_items,
    unsigned short* __restrict__ ugen_b, unsigned short* __restrict__ uio_b,
    unsigned short* __restrict__ igen_b, unsigned short* __restrict__ iio_b,
    float* __restrict__ posu, float* __restrict__ posi,
    double* __restrict__ bprp, double* __restrict__ esp) {
  __shared__ __align__(16) unsigned short sUIT[128 * 72];
  __shared__ __align__(16) unsigned short sUI[64 * 136];
  __shared__ __align__(16) unsigned short sP[4][16 * 136];
  __shared__ double red[8];
  int bid = blockIdx.x;
  int lane = threadIdx.x & 63;
  int wid = threadIdx.x >> 6;
  int n = lane & 15, q = lane >> 4;
  int isI = bid >> 6;
  int i0 = ((bid & 63) << 6) + wid * 16;
  const float* intent = isI ? item_int : user_int;
  for (int i = threadIdx.x; i < 8192; i += 256) {
    int dd = i >> 7, kk = i & 127;
    unsigned short v = f2b(intent[i]);
    sUIT[kk * 72 + dd] = v;
    sUI[dd * 136 + kk] = v;
  }
  __syncthreads();
  unsigned short* myP = &sP[wid][0];
  int piN = pos_items[i0 + n];
  int rw = isI ? (NU + piN) : users[i0 + n];
  const unsigned short* arp = accB + (size_t)rw * 64;
  bf16x8 a0 = *(const bf16x8*)(arp + q * 8);
  bf16x8 a1 = *(const bf16x8*)(arp + 32 + q * 8);
  // logits: c[kt](item q*4+r, k=kt*16+n)
  f32x4 c[8];
#pragma unroll
  for (int kt = 0; kt < 8; kt++) {
    const unsigned short* bp = &sUIT[(kt * 16 + n) * 72 + q * 8];
    bf16x8 b0 = *(const bf16x8*)bp;
    bf16x8 b1 = *(const bf16x8*)(bp + 32);
    f32x4 z = {0.f, 0.f, 0.f, 0.f};
    z = __builtin_amdgcn_mfma_f32_16x16x32_bf16(a0, b0, z, 0, 0, 0);
    c[kt] = __builtin_amdgcn_mfma_f32_16x16x32_bf16(a1, b1, z, 0, 0, 0);
  }
  // softmax over k per item
  float mx[4], tot[4];
#pragma unroll
  for (int r = 0; r < 4; r++) {
    float m = c[0][r];
#pragma unroll
    for (int kt = 1; kt < 8; kt++) m = fmaxf(m, c[kt][r]);
#pragma unroll
    for (int o = 1; o < 16; o <<= 1) m = fmaxf(m, __shfl_xor(m, o, 64));
    mx[r] = m;
  }
#pragma unroll
  for (int kt = 0; kt < 8; kt++)
#pragma unroll
    for (int r = 0; r < 4; r++) c[kt][r] = __expf(c[kt][r] - mx[r]);
#pragma unroll
  for (int r = 0; r < 4; r++) {
    float t = 0.f;
#pragma unroll
    for (int kt = 0; kt < 8; kt++) t += c[kt][r];
#pragma unroll
    for (int o = 1; o < 16; o <<= 1) t += __shfl_xor(t, o, 64);
    tot[r] = 1.f / t;
  }
  // P -> LDS (bf16, item-row-major)
#pragma unroll
  for (int kt = 0; kt < 8; kt++)
#pragma unroll
    for (int r = 0; r < 4; r++)
      myP[(q * 4 + r) * 136 + kt * 16 + n] = f2b(c[kt][r] * tot[r]);
  // PV: s[dt](item q*4+r, d=dt*16+n)
  f32x4 s[4];
#pragma unroll
  for (int dt = 0; dt < 4; dt++) s[dt] = (f32x4){0.f, 0.f, 0.f, 0.f};
#pragma unroll
  for (int cc = 0; cc < 4; cc++) {
    bf16x8 pa = *(const bf16x8*)&myP[n * 136 + cc * 32 + q * 8];
#pragma unroll
    for (int dt = 0; dt < 4; dt++) {
      bf16x8 bb = *(const bf16x8*)&sUI[(dt * 16 + n) * 136 + cc * 32 + q * 8];
      s[dt] = __builtin_amdgcn_mfma_f32_16x16x32_bf16(pa, bb, s[dt], 0, 0, 0);
    }
  }
  // io = normalize(s)
  float rin[4];
#pragma unroll
  for (int r = 0; r < 4; r++) {
    float t = 0.f;
#pragma unroll
    for (int dt = 0; dt < 4; dt++) t += s[dt][r] * s[dt][r];
#pragma unroll
    for (int o = 1; o < 16; o <<= 1) t += __shfl_xor(t, o, 64);
    rin[r] = 1.f / sqrtf(t);
  }
  float iov[4][4];
  unsigned short* iob = isI ? iio_b : uio_b;
#pragma unroll
  for (int dt = 0; dt < 4; dt++)
#pragma unroll
    for (int r = 0; r < 4; r++) {
      float v = s[dt][r] * rin[r];
      iov[dt][r] = v;
      iob[(size_t)(i0 + q * 4 + r) * 64 + dt * 16 + n] = f2b(v);
    }
  // sd via K=32 MFMA: A3 = softplus(m[:, :32])
  bf16x8 A3;
#pragma unroll
  for (int j = 0; j < 8; j++) A3[j] = (short)f2b(softplusf(bfe(a0, j)));
  f32x4 sd4[4];
  float lbv[4];
#pragma unroll
  for (int dt = 0; dt < 4; dt++) {
    const float* wp = lin_w + (size_t)(dt * 16 + n) * 32 + q * 8;
    float4 w0 = *(const float4*)wp;
    float4 w1 = *(const float4*)(wp + 4);
    bf16x8 B3;
    B3[0] = (short)f2b(w0.x); B3[1] = (short)f2b(w0.y);
    B3[2] = (short)f2b(w0.z); B3[3] = (short)f2b(w0.w);
    B3[4] = (short)f2b(w1.x); B3[5] = (short)f2b(w1.y);
    B3[6] = (short)f2b(w1.z); B3[7] = (short)f2b(w1.w);
    f32x4 z = {0.f, 0.f, 0.f, 0.f};
    sd4[dt] = __builtin_amdgcn_mfma_f32_16x16x32_bf16(A3, B3, z, 0, 0, 0);
    lbv[dt] = lin_b[dt * 16 + n];
  }
  // m -> C-layout via LDS (raw frags ARE the row data)
  *(bf16x8*)&myP[n * 136 + q * 8] = a0;
  *(bf16x8*)&myP[n * 136 + 32 + q * 8] = a1;
  int rwr[4];
#pragma unroll
  for (int r = 0; r < 4; r++) rwr[r] = __shfl(rw, q * 4 + r, 64);
  float ge[4][4];
#pragma unroll
  for (int dt = 0; dt < 4; dt++)
#pragma unroll
    for (int r = 0; r < 4; r++) {
      float mcv = b2f(myP[(q * 4 + r) * 136 + dt * 16 + n]);
      float ep = eps[(size_t)rwr[r] * 64 + dt * 16 + n];
      float sdf = sd4[dt][r] + lbv[dt] + 1e-8f;
      ge[dt][r] = mcv + ep * sdf;
    }
  float gin[4];
#pragma unroll
  for (int r = 0; r < 4; r++) {
    float t = 0.f;
#pragma unroll
    for (int dt = 0; dt < 4; dt++) t += ge[dt][r] * ge[dt][r];
#pragma unroll
    for (int o = 1; o < 16; o <<= 1) t += __shfl_xor(t, o, 64);
    gin[r] = 1.f / sqrtf(t);
  }
  float pd[4] = {0.f, 0.f, 0.f, 0.f};
  unsigned short* gob = isI ? igen_b : ugen_b;
#pragma unroll
  for (int dt = 0; dt < 4; dt++)
#pragma unroll
    for (int r = 0; r < 4; r++) {
      float go = ge[dt][r] * gin[r];
      gob[(size_t)(i0 + q * 4 + r) * 64 + dt * 16 + n] = f2b(go);
      pd[r] = fmaf(go, iov[dt][r], pd[r]);
    }
  float* posX = isI ? posi : posu;
#pragma unroll
  for (int r = 0; r < 4; r++) {
    float t = pd[r];
#pragma unroll
    for (int o = 1; o < 16; o <<= 1) t += __shfl_xor(t, o, 64);
    if (n == 0) posX[i0 + q * 4 + r] = t;
  }
  // side-specific reductions -> per-block scratch slots (no atomics)
  if (!isI) {
    int niN = neg_items[i0 + n];
    const unsigned short* pp = accB + (size_t)(NU + piN) * 64;
    const unsigned short* np = accB + (size_t)(NU + niN) * 64;
    bf16x8 p0 = *(const bf16x8*)(pp + q * 8);
    bf16x8 p1 = *(const bf16x8*)(pp + 32 + q * 8);
    bf16x8 n0 = *(const bf16x8*)(np + q * 8);
    bf16x8 n1 = *(const bf16x8*)(np + 32 + q * 8);
    float ps = 0.f, ns = 0.f;
#pragma unroll
    for (int j = 0; j < 8; j++) {
      float m0 = bfe(a0, j), m1 = bfe(a1, j);
      ps = fmaf(m0, bfe(p0, j), ps); ps = fmaf(m1, bfe(p1, j), ps);
      ns = fmaf(m0, bfe(n0, j), ns); ns = fmaf(m1, bfe(n1, j), ns);
    }
    ps += __shfl_xor(ps, 16, 64); ps += __shfl_xor(ps, 32, 64);
    ns += __shfl_xor(ns, 16, 64); ns += __shfl_xor(ns, 32, 64);
    float bpr = softplusf(ns - ps);
    const float* uep = user_emb + (size_t)rw * 64 + q * 16;
    float es = 0.f;
#pragma unroll
    for (int j = 0; j < 4; j++) {
      float4 u4 = *(const float4*)(uep + j * 4);
      es += u4.x * u4.x + u4.y * u4.y + u4.z * u4.z + u4.w * u4.w;
    }
    es += __shfl_xor(es, 16, 64); es += __shfl_xor(es, 32, 64);
#pragma unroll
    for (int o = 1; o < 16; o <<= 1) {
      bpr += __shfl_xor(bpr, o, 64);
      es += __shfl_xor(es, o, 64);
    }
    if (lane == 0) { red[wid] = (double)bpr; red[4 + wid] = (double)es; }
    __syncthreads();
    if (threadIdx.x == 0) {
      bprp[bid] = red[0] + red[1] + red[2] + red[3];
      esp[bid] = red[4] + red[5] + red[6] + red[7];
    }
  } else {
    int niN = neg_items[i0 + n];
    const float* pe = item_emb + (size_t)piN * 64 + q * 16;
    const float* ne = item_emb + (size_t)niN * 64 + q * 16;
    float es = 0.f;
#pragma unroll
    for (int j = 0; j < 4; j++) {
      float4 u4 = *(const float4*)(pe + j * 4);
      float4 v4 = *(const float4*)(ne + j * 4);
      es += u4.x * u4.x + u4.y * u4.y + u4.z * u4.z + u4.w * u4.w;
      es += v4.x * v4.x + v4.y * v4.y + v4.z * v4.z + v4.w * v4.w;
    }
    es += __shfl_xor(es, 16, 64); es += __shfl_xor(es, 32, 64);
#pragma unroll
    for (int o = 1; o < 16; o <<= 1) es += __shfl_xor(es, o, 64);
    if (lane == 0) red[wid] = (double)es;
    __syncthreads();
    if (threadIdx.x == 0)
      esp[bid] = red[0] + red[1] + red[2] + red[3];
  }
}

// ---------------- nce + KL + int (merged grid, nce LDS-staged) ----------------
__global__ __launch_bounds__(256) void k_nk(
    const unsigned short* __restrict__ e1u, const unsigned short* __restrict__ e2u,
    const unsigned short* __restrict__ e1i, const unsigned short* __restrict__ e2i,
    float* __restrict__ negu, float* __restrict__ negi,
    const unsigned short* __restrict__ accB,
    const float* __restrict__ lin_w, const float* __restrict__ lin_b,
    const float* __restrict__ user_int, const float* __restrict__ item_int,
    double* __restrict__ klp, double* __restrict__ intp) {
  __shared__ double red[4];
  __shared__ __align__(16) uint4 sE2[2048];  // 256 rows x 128B, swizzled
  int bid = blockIdx.x;
  int lane = threadIdx.x & 63;
  int wid = threadIdx.x >> 6;
  int n = lane & 15, q = lane >> 4;
  if (bid < 2048) {
    // ---- InfoNCE negatives (bf16 MFMA), j split 16-way, LDS-staged ----
    int bx = bid & 63, by = bid >> 6;
    int pr = by >> 4, jq = by & 15;
    const unsigned short* e1 = pr ? e1i : e1u;
    const unsigned short* e2 = pr ? e2i : e2u;
    float* nego = pr ? negi : negu;
    const uint4* e2v = (const uint4*)e2 + (size_t)jq * 2048;
#pragma unroll
    for (int k = 0; k < 8; k++) {
      int i = (int)threadIdx.x + k * 256;
      int row = i >> 3, cch = i & 7;
      sE2[(i & ~7) | (cch ^ (row & 7))] = e2v[i];
    }
    int i0 = bx * 64 + wid * 16;
    const bf16x8* arow = (const bf16x8*)(e1 + (size_t)(i0 + n) * 64 + q * 8);
    bf16x8 a0 = arow[0];
    bf16x8 a1 = arow[4];
    __syncthreads();
    f32x4 accv = {0.f, 0.f, 0.f, 0.f};
    int sw = n & 7;
    for (int jt = 0; jt < 16; jt += 2) {
      int r0 = jt * 16 + n;
      const uint4* base0 = &sE2[r0 * 8];
      const uint4* base1 = &sE2[(r0 + 16) * 8];
      bf16x8 b0 = *(const bf16x8*)&base0[q ^ sw];
      bf16x8 b1 = *(const bf16x8*)&base0[(q + 4) ^ sw];
      bf16x8 b2 = *(const bf16x8*)&base1[q ^ sw];
      bf16x8 b3 = *(const bf16x8*)&base1[(q + 4) ^ sw];
      f32x4 c = {0.f, 0.f, 0.f, 0.f};
      f32x4 c2 = {0.f, 0.f, 0.f, 0.f};
      c = __builtin_amdgcn_mfma_f32_16x16x32_bf16(a0, b0, c, 0, 0, 0);
      c = __builtin_amdgcn_mfma_f32_16x16x32_bf16(a1, b1, c, 0, 0, 0);
      c2 = __builtin_amdgcn_mfma_f32_16x16x32_bf16(a0, b2, c2, 0, 0, 0);
      c2 = __builtin_amdgcn_mfma_f32_16x16x32_bf16(a1, b3, c2, 0, 0, 0);
#pragma unroll
      for (int r = 0; r < 4; r++)
        accv[r] += __expf(5.0f * c[r]) + __expf(5.0f * c2[r]);
    }
#pragma unroll
    for (int o = 1; o < 16; o <<= 1) {
#pragma unroll
      for (int r = 0; r < 4; r++) accv[r] += __shfl_xor(accv[r], o, 64);
    }
    if (n == 0) {
#pragma unroll
      for (int r = 0; r < 4; r++) atomicAdd(&nego[i0 + q * 4 + r], accv[r]);
    }
  } else if (bid < 2048 + KLB) {
    // ---- KL branch (MFMA over bf16 acc; partial->slot; 16B loads) ----
    bf16x8 B0, B1, B2, B3;
    float lb0, lb1, lb2, lb3;
    {
      const float* w0 = lin_w + (0 * 16 + n) * 32 + q * 8;
      const float* w1 = lin_w + (1 * 16 + n) * 32 + q * 8;
      const float* w2 = lin_w + (2 * 16 + n) * 32 + q * 8;
      const float* w3 = lin_w + (3 * 16 + n) * 32 + q * 8;
#pragma unroll
      for (int j = 0; j < 8; j++) {
        B0[j] = (short)f2b(w0[j]);
        B1[j] = (short)f2b(w1[j]);
        B2[j] = (short)f2b(w2[j]);
        B3[j] = (short)f2b(w3[j]);
      }
      lb0 = lin_b[0 * 16 + n] + 1e-8f;
      lb1 = lin_b[1 * 16 + n] + 1e-8f;
      lb2 = lin_b[2 * 16 + n] + 1e-8f;
      lb3 = lin_b[3 * 16 + n] + 1e-8f;
    }
    const int TI = NT / 16;
    int w0id = (bid - 2048) * 4 + wid;
    int nwv = KLB * 4;
    double dsum = 0.0;
    for (int tile = w0id; tile < TI; tile += nwv) {
      const uint4* rp = (const uint4*)(accB + (size_t)(tile * 16 + n) * 64 + q * 8);
      uint4 A = rp[0];
      uint4 C = rp[4];   // +32 dims = +64B = +4 uint4
      u64 A0 = ((u64)A.y << 32) | A.x;
      u64 A1 = ((u64)A.w << 32) | A.z;
      u64 C0 = ((u64)C.y << 32) | C.x;
      u64 C1 = ((u64)C.w << 32) | C.z;
      float av[8], bv[8];
      unp4(A0, av); unp4(A1, av + 4);
      unp4(C0, bv); unp4(C1, bv + 4);
      float msum = 0.f;
#pragma unroll
      for (int j = 0; j < 8; j++) msum += av[j] * av[j] + bv[j] * bv[j];
      bf16x8 Af;
#pragma unroll
      for (int j = 0; j < 8; j++) Af[j] = (short)f2b(softplusf(av[j]));
      f32x4 z = {0.f, 0.f, 0.f, 0.f};
      f32x4 c0 = __builtin_amdgcn_mfma_f32_16x16x32_bf16(Af, B0, z, 0, 0, 0);
      f32x4 c1 = __builtin_amdgcn_mfma_f32_16x16x32_bf16(Af, B1, z, 0, 0, 0);
      f32x4 c2 = __builtin_amdgcn_mfma_f32_16x16x32_bf16(Af, B2, z, 0, 0, 0);
      f32x4 c3 = __builtin_amdgcn_mfma_f32_16x16x32_bf16(Af, B3, z, 0, 0, 0);
      float ksum = 0.f;
#pragma unroll
      for (int r = 0; r < 4; r++) {
        float s0 = c0[r] + lb0, s1 = c1[r] + lb1, s2 = c2[r] + lb2, s3 = c3[r] + lb3;
        ksum += -0.5f * (1.f + 2.f * s0 - __expf(2.f * s0));
        ksum += -0.5f * (1.f + 2.f * s1 - __expf(2.f * s1));
        ksum += -0.5f * (1.f + 2.f * s2 - __expf(2.f * s2));
        ksum += -0.5f * (1.f + 2.f * s3 - __expf(2.f * s3));
      }
      dsum += (double)wsum(ksum + 0.5f * msum);
    }
    if (lane == 0) red[wid] = dsum;
    __syncthreads();
    if (threadIdx.x == 0)
      klp[bid - 2048] = red[0] + red[1] + red[2] + red[3];
  } else {
    // ---- int_loss block ----
    float s = 0.f;
    for (int i = threadIdx.x; i < 64 * 128; i += 256) {
      float a = user_int[i], b = item_int[i];
      s = fmaf(a, a, s);
      s = fmaf(b, b, s);
    }
    s = wsum(s);
    if (lane == 0) red[wid] = (double)s;
    __syncthreads();
    if (threadIdx.x == 0)
      intp[0] = red[0] + red[1] + red[2] + red[3];
  }
}

// final combine: partial-array sums + nce log-sum + output assembly (1 block)
__global__ __launch_bounds__(256) void k_out(
    const float* __restrict__ posu, const float* __restrict__ posi,
    const float* __restrict__ negu, const float* __restrict__ negi,
    const double* __restrict__ bprp, const double* __restrict__ esp,
    const double* __restrict__ klp, const double* __restrict__ intp,
    float* __restrict__ out) {
  __shared__ double redd[16];
  int tid = threadIdx.x;
  int lane = tid & 63, wid = tid >> 6;
  double cl = 0.0;
  for (int i = tid; i < 2 * BB; i += 256) {
    int pr = i >> 12, idx = i & (BB - 1);
    float ng = pr ? negi[idx] : negu[idx];
    float dt = pr ? posi[idx] : posu[idx];
    float pos = expf(5.0f * dt);
    cl += (double)(-logf(pos / (ng + 1e-8f) + 1e-8f));
  }
  double kl = 0.0;
  for (int i = tid; i < KLB; i += 256) kl += klp[i];
  double bpr = (tid < 64) ? bprp[tid] : 0.0;
  double es = (tid < 128) ? esp[tid] : 0.0;
#pragma unroll
  for (int o = 32; o > 0; o >>= 1) {
    cl += __shfl_xor(cl, o, 64);
    kl += __shfl_xor(kl, o, 64);
    bpr += __shfl_xor(bpr, o, 64);
    es += __shfl_xor(es, o, 64);
  }
  if (lane == 0) {
    redd[wid] = cl; redd[4 + wid] = kl;
    redd[8 + wid] = bpr; redd[12 + wid] = es;
  }
  __syncthreads();
  if (tid == 0) {
    double cls = redd[0] + redd[1] + redd[2] + redd[3];
    double kls = redd[4] + redd[5] + redd[6] + redd[7];
    double bprs = redd[8] + redd[9] + redd[10] + redd[11];
    double ess = redd[12] + redd[13] + redd[14] + redd[15];
    out[0] = (float)(bprs / (double)BB + 0.01 * kls / (double)NT);
    out[1] = (float)(0.1 * cls / (double)BB);
    out[2] = (float)(1e-5 * ess);
    out[3] = (float)(1e-5 * intp[0]);
  }
}

extern "C" void kernel_launch(void* const* d_in, const int* in_sizes, int n_in,
                              void* d_out, int out_size, void* d_ws, size_t ws_size,
                              hipStream_t stream) {
  const float* user_emb = (const float*)d_in[0];
  const float* item_emb = (const float*)d_in[1];
  const float* user_int = (const float*)d_in[2];
  const float* item_int = (const float*)d_in[3];
  const float* lin_w = (const float*)d_in[4];
  const float* lin_b = (const float*)d_in[5];
  const float* eps = (const float*)d_in[6];
  const int* h_list = (const int*)d_in[7];
  const int* t_list = (const int*)d_in[8];
  const int* users = (const int*)d_in[9];
  const int* pos_items = (const int*)d_in[10];
  const int* neg_items = (const int*)d_in[11];
  float* out = (float*)d_out;
  const int E = in_sizes[7];

  char* ws = (char*)d_ws;
  size_t off = 0;
  auto take = [&](size_t bytes) -> char* {
    char* p = ws + off;
    off = (off + bytes + 255) & ~(size_t)255;
    return p;
  };
  // zeroed region: deg (NTP ints) + negu + negi — ONE memset covers all
  char* zws = take((size_t)NTP * 4 + (size_t)BB * 4 * 2);
  int* deg = (int*)zws;
  float* negu = (float*)(zws + (size_t)NTP * 4);
  float* negi = negu + BB;
  int* row_ptr = (int*)take((size_t)(NT + 1) * 4);
  float* d_inv = (float*)take((size_t)NTP * 4);
  int* rloc_g = (int*)take((size_t)NTP * 4);
  int* cursor = (int*)take((size_t)NTP * 4);
  int* btot = (int*)take(147 * 4);
  uint2* edges = (uint2*)take((size_t)E * 8);
  unsigned* bufA = (unsigned*)take((size_t)NT * 16 * 4);  // fp8 rows (16 dwords)
  unsigned* bufB = (unsigned*)take((size_t)NT * 16 * 4);
  unsigned short* accB = (unsigned short*)take((size_t)NT * 64 * 2);
  unsigned short* ugen_b = (unsigned short*)take((size_t)BB * 64 * 2);
  unsigned short* igen_b = (unsigned short*)take((size_t)BB * 64 * 2);
  unsigned short* uio_b = (unsigned short*)take((size_t)BB * 64 * 2);
  unsigned short* iio_b = (unsigned short*)take((size_t)BB * 64 * 2);
  float* posu = (float*)take((size_t)BB * 4);
  float* posi = (float*)take((size_t)BB * 4);
  double* klp = (double*)take((size_t)KLB * 8);
  double* bprp = (double*)take(64 * 8);
  double* esp = (double*)take(128 * 8);
  double* intp = (double*)take(8);
  if (off > ws_size) return;
  u64* acc64 = (u64*)accB;

  hipMemsetAsync(zws, 0, (size_t)NTP * 4 + (size_t)BB * 4 * 2, stream);

  int gridE = (E + 1023) / 1024;
  k_deg<<<gridE, 256, 0, stream>>>(h_list, deg, E);
  k_scan1<<<147, 256, 0, stream>>>(deg, rloc_g, d_inv, btot);
  k_scan2<<<(NT + 255) / 256, 256, 0, stream>>>(btot, rloc_g, row_ptr, cursor);
  k_place<<<gridE, 256, 0, stream>>>(h_list, t_list, cursor, d_inv, edges, E);

  int nU4 = NU * 16, nTot4 = NT * 16;
  k_init<<<(nTot4 + 255) / 256, 256, 0, stream>>>((const float4*)user_emb,
                                                  (const float4*)item_emb, bufA,
                                                  acc64, nU4, nTot4);
  int gridAgg = NT / 8;
  k_agg<<<gridAgg, 256, 0, stream>>>(row_ptr, edges, bufA, bufB, acc64, 0);
  k_agg<<<gridAgg, 256, 0, stream>>>(row_ptr, edges, bufB, bufA, acc64, 0);
  k_agg<<<gridAgg, 256, 0, stream>>>(row_ptr, edges, bufA, bufB, acc64, 1);

  k_batch<<<128, 256, 0, stream>>>(accB, user_emb, item_emb, eps,
                                   user_int, item_int, lin_w, lin_b,
                                   users, pos_items, neg_items,
                                   ugen_b, uio_b, igen_b, iio_b,
                                   posu, posi, bprp, esp);
  k_nk<<<2048 + KLB + 1, 256, 0, stream>>>(ugen_b, uio_b, igen_b, iio_b,
                                           negu, negi, accB, lin_w, lin_b,
                                           user_int, item_int, klp, intp);
  k_out<<<1, 256, 0, stream>>>(posu, posi, negu, negi, bprp, esp, klp, intp,
                               out);
}

// Round 13
// 422.683 us; speedup vs baseline: 1.3952x; 1.3952x over previous
//
#include <hip/hip_runtime.h>

#define NU 50000
#define NI 100000
#define NT 150000
#define BB 4096
#define NBUCK 147   // ceil(NT/1024)
#define BCAP 24576  // per-bucket edge capacity: mean 21504, sd ~143 -> +21 sigma
#define NCH 8       // chunks per bucket in CSR build
#define KLB 1920    // KL blocks

typedef __attribute__((ext_vector_type(8))) short bf16x8;
typedef __attribute__((ext_vector_type(4))) float f32x4;
typedef __attribute__((ext_vector_type(2))) float f32x2;
typedef unsigned long long u64;

__device__ __forceinline__ float softplusf(float x) {
  return fmaxf(x, 0.f) + __logf(1.f + __expf(-fabsf(x)));
}
__device__ __forceinline__ float wsum(float v) {
#pragma unroll
  for (int o = 32; o > 0; o >>= 1) v += __shfl_xor(v, o, 64);
  return v;
}
__device__ __forceinline__ unsigned short f2b(float x) {
  unsigned u = __float_as_uint(x);
  return (unsigned short)((u + 0x7FFFu + ((u >> 16) & 1u)) >> 16);
}
__device__ __forceinline__ float b2f(unsigned us) {  // low 16 bits = bf16
  return __uint_as_float(us << 16);
}
__device__ __forceinline__ float bfe(bf16x8 v, int j) {  // frag elem -> f32
  return __uint_as_float(((unsigned)(unsigned short)v[j]) << 16);
}
__device__ __forceinline__ void unp4(u64 v, float* o) {
  unsigned lo = (unsigned)v, hi = (unsigned)(v >> 32);
  o[0] = __uint_as_float(lo << 16);
  o[1] = __uint_as_float(lo & 0xffff0000u);
  o[2] = __uint_as_float(hi << 16);
  o[3] = __uint_as_float(hi & 0xffff0000u);
}
__device__ __forceinline__ u64 pk4(float x0, float x1, float x2, float x3) {
  return (u64)((unsigned)f2b(x0) | ((unsigned)f2b(x1) << 16)) |
         ((u64)((unsigned)f2b(x2) | ((unsigned)f2b(x3) << 16)) << 32);
}
// real packed dual-FMA (VOP3P) — compiler scalarizes float2 '+=', force it.
__device__ __forceinline__ f32x2 pkfma(f32x2 a, f32x2 b, f32x2 c) {
  f32x2 d;
  asm("v_pk_fma_f32 %0, %1, %2, %3" : "=v"(d) : "v"(a), "v"(b), "v"(c));
  return d;
}

// ---------------- setup ----------------
__global__ void k_zero(int* __restrict__ gcur, float* __restrict__ negu,
                       float* __restrict__ negi) {
  int t = threadIdx.x;
  for (int i = t; i < NBUCK; i += 256) gcur[i] = 0;
  for (int i = t; i < BB; i += 256) { negu[i] = 0.f; negi[i] = 0.f; }
}

// ---------------- CSR build (bucket-staged; round-12 lesson: direct
// per-edge global scatter costs 8x write amplification across XCDs) -------
__global__ __launch_bounds__(256) void k_part(const int* __restrict__ h,
                                              const int* __restrict__ t,
                                              int* __restrict__ gcur,
                                              uint2* __restrict__ part, int E) {
  __shared__ int cnt[NBUCK];
  __shared__ int base[NBUCK];
  for (int b = threadIdx.x; b < NBUCK; b += 256) cnt[b] = 0;
  __syncthreads();
  int e0 = blockIdx.x * 4096 + threadIdx.x * 16;
  int nval = E - e0;
  nval = nval < 0 ? 0 : (nval > 16 ? 16 : nval);
  int hh[16], tt[16];
  if (nval == 16) {
    const int4* hp = (const int4*)(h + e0);
    const int4* tp = (const int4*)(t + e0);
#pragma unroll
    for (int j = 0; j < 4; j++) {
      int4 v = hp[j];
      hh[j * 4] = v.x; hh[j * 4 + 1] = v.y; hh[j * 4 + 2] = v.z; hh[j * 4 + 3] = v.w;
      int4 w = tp[j];
      tt[j * 4] = w.x; tt[j * 4 + 1] = w.y; tt[j * 4 + 2] = w.z; tt[j * 4 + 3] = w.w;
    }
  } else {
    for (int j = 0; j < nval; j++) { hh[j] = h[e0 + j]; tt[j] = t[e0 + j]; }
  }
  for (int j = 0; j < nval; j++) atomicAdd(&cnt[hh[j] >> 10], 1);
  __syncthreads();
  for (int b = threadIdx.x; b < NBUCK; b += 256) {
    int c = cnt[b];
    base[b] = c ? atomicAdd(&gcur[b], c) : 0;
    cnt[b] = 0;
  }
  __syncthreads();
  for (int j = 0; j < nval; j++) {
    int b = hh[j] >> 10;
    int r = atomicAdd(&cnt[b], 1);
    uint2 v; v.x = (unsigned)hh[j]; v.y = (unsigned)tt[j];
    part[(size_t)b * BCAP + base[b] + r] = v;
  }
}

// cnt_chunk layout: [(b<<10)+n][c] (node-major, chunk-minor)
__global__ __launch_bounds__(256) void k_count2(const uint2* __restrict__ part,
                                                const int* __restrict__ gcur,
                                                int* __restrict__ cnt_chunk) {
  __shared__ int hist[1024];
  int b = blockIdx.x, c = blockIdx.y, tid = threadIdx.x;
  for (int i = tid; i < 1024; i += 256) hist[i] = 0;
  __syncthreads();
  int m = gcur[b];
  int lo = (int)(((long long)m * c) >> 3);
  int hi = (int)(((long long)m * (c + 1)) >> 3);
  const uint2* pp = part + (size_t)b * BCAP;
  for (int i = lo + tid; i < hi; i += 256) atomicAdd(&hist[pp[i].x & 1023], 1);
  __syncthreads();
  for (int i = tid; i < 1024; i += 256)
    cnt_chunk[((((size_t)b << 10) + i) << 3) + c] = hist[i];
}

__global__ __launch_bounds__(256) void k_node(int* __restrict__ cnt_chunk,
                                              int* __restrict__ rloc_g,
                                              float* __restrict__ d_inv,
                                              int* __restrict__ btot) {
  __shared__ int sd[256];
  int b = blockIdx.x, tid = threadIdx.x;
  int n0 = b << 10;
  int pd[4];
  int s = 0;
#pragma unroll
  for (int j = 0; j < 4; j++) {
    int idx = tid * 4 + j;
    size_t base = ((size_t)(n0 + idx)) << 3;
    int run = 0;
#pragma unroll
    for (int c = 0; c < NCH; c++) {
      int v = cnt_chunk[base + c];
      cnt_chunk[base + c] = run;
      run += v;
    }
    int n = n0 + idx;
    if (n < NT) {
      d_inv[n] = 1.0f / sqrtf((float)run);  // deg >= 1 (self-loop)
      pd[j] = run;
    } else pd[j] = 0;
    s += pd[j];
  }
  sd[tid] = s;
  __syncthreads();
  for (int o = 1; o < 256; o <<= 1) {
    int x = (tid >= o) ? sd[tid - o] : 0;
    __syncthreads();
    sd[tid] += x;
    __syncthreads();
  }
  int run2 = sd[tid] - s;
#pragma unroll
  for (int j = 0; j < 4; j++) {
    int idx = tid * 4 + j, n = n0 + idx;
    if (n < NT) rloc_g[n] = run2;
    run2 += pd[j];
  }
  if (tid == 255) btot[b] = sd[255];
}

// k_rowptr folded in: every block redoes the cheap 147-entry scan of btot,
// c==0 blocks write row_ptr for their bucket.
__global__ __launch_bounds__(256) void k_fill2(const uint2* __restrict__ part,
                                               const int* __restrict__ gcur,
                                               const int* __restrict__ chunkpre,
                                               const int* __restrict__ rloc_g,
                                               const int* __restrict__ btot,
                                               const float* __restrict__ d_inv,
                                               uint2* __restrict__ edges,
                                               int* __restrict__ row_ptr) {
  __shared__ int curs[1024];
  __shared__ float dl[1024];
  __shared__ int sd[256];
  __shared__ int exs[256];
  int b = blockIdx.x, c = blockIdx.y, tid = threadIdx.x;
  int v = (tid < NBUCK) ? btot[tid] : 0;
  sd[tid] = v;
  __syncthreads();
  for (int o = 1; o < 256; o <<= 1) {
    int x = (tid >= o) ? sd[tid - o] : 0;
    __syncthreads();
    sd[tid] += x;
    __syncthreads();
  }
  exs[tid] = sd[tid] - v;
  __syncthreads();
  int exB = exs[b];
  int n0 = b << 10;
  for (int i = tid; i < 1024; i += 256) {
    int n = n0 + i;
    if (n < NT) {
      int rp = exB + rloc_g[n];
      curs[i] = rp + chunkpre[((((size_t)b << 10) + i) << 3) + c];
      dl[i] = d_inv[n];
      if (c == 0) row_ptr[n] = rp;
    }
  }
  if (c == 0 && b == 0 && tid == 0) row_ptr[NT] = exs[255];
  __syncthreads();
  int m = gcur[b];
  int lo = (int)(((long long)m * c) >> 3);
  int hi = (int)(((long long)m * (c + 1)) >> 3);
  const uint2* pp = part + (size_t)b * BCAP;
  for (int i = lo + tid; i < hi; i += 256) {
    uint2 pe = pp[i];
    int slot = atomicAdd(&curs[pe.x & 1023], 1);
    float g = dl[pe.x & 1023] * d_inv[pe.y];
    uint2 w; w.x = pe.y; w.y = __float_as_uint(g);
    edges[slot] = w;
  }
}

// ---------------- propagation ----------------
__global__ void k_init(const float4* __restrict__ ue, const float4* __restrict__ ie,
                       unsigned* __restrict__ cur, u64* __restrict__ acc64,
                       int nU4, int nTot4) {
  int i = blockIdx.x * 256 + threadIdx.x;
  if (i >= nTot4) return;
  float4 v = (i < nU4) ? ue[i] : ie[i - nU4];
  int p = __builtin_amdgcn_cvt_pk_fp8_f32(v.x, v.y, 0, false);
  p = __builtin_amdgcn_cvt_pk_fp8_f32(v.z, v.w, p, true);
  cur[i] = (unsigned)p;
  acc64[i] = pk4(v.x, v.y, v.z, v.w);
}

// 32-edge step for one node: 2 record loads + 8 gathers + 16 cvt + 16 pk_fma.
__device__ __forceinline__ void agg32(const u64* __restrict__ ep,
                                      const unsigned* __restrict__ cur,
                                      int i, int e, int d, int b4,
                                      f32x2& a01, f32x2& a23) {
  int ia = i + d;
  int ib = ia + 16;
  u64 ra = ep[ia < e ? ia : e - 1];
  u64 rb = ep[ib < e ? ib : e - 1];
  unsigned rax = (unsigned)ra;
  unsigned ray = (ia < e) ? (unsigned)(ra >> 32) : 0u;
  unsigned rbx = (unsigned)rb;
  unsigned rby = (ib < e) ? (unsigned)(rb >> 32) : 0u;
  unsigned iA0 = __shfl(rax, b4 + 0, 64); float gA0 = __uint_as_float(__shfl(ray, b4 + 0, 64));
  unsigned iA1 = __shfl(rax, b4 + 1, 64); float gA1 = __uint_as_float(__shfl(ray, b4 + 1, 64));
  unsigned iA2 = __shfl(rax, b4 + 2, 64); float gA2 = __uint_as_float(__shfl(ray, b4 + 2, 64));
  unsigned iA3 = __shfl(rax, b4 + 3, 64); float gA3 = __uint_as_float(__shfl(ray, b4 + 3, 64));
  unsigned vA0 = cur[(iA0 << 4) + (unsigned)d];
  unsigned vA1 = cur[(iA1 << 4) + (unsigned)d];
  unsigned vA2 = cur[(iA2 << 4) + (unsigned)d];
  unsigned vA3 = cur[(iA3 << 4) + (unsigned)d];
  unsigned iB0 = __shfl(rbx, b4 + 0, 64); float gB0 = __uint_as_float(__shfl(rby, b4 + 0, 64));
  unsigned iB1 = __shfl(rbx, b4 + 1, 64); float gB1 = __uint_as_float(__shfl(rby, b4 + 1, 64));
  unsigned iB2 = __shfl(rbx, b4 + 2, 64); float gB2 = __uint_as_float(__shfl(rby, b4 + 2, 64));
  unsigned iB3 = __shfl(rbx, b4 + 3, 64); float gB3 = __uint_as_float(__shfl(rby, b4 + 3, 64));
  unsigned vB0 = cur[(iB0 << 4) + (unsigned)d];
  unsigned vB1 = cur[(iB1 << 4) + (unsigned)d];
  unsigned vB2 = cur[(iB2 << 4) + (unsigned)d];
  unsigned vB3 = cur[(iB3 << 4) + (unsigned)d];
  f32x2 g2;
  g2.x = gA0; g2.y = gA0;
  a01 = pkfma(__builtin_amdgcn_cvt_pk_f32_fp8(vA0, false), g2, a01);
  a23 = pkfma(__builtin_amdgcn_cvt_pk_f32_fp8(vA0, true), g2, a23);
  g2.x = gA1; g2.y = gA1;
  a01 = pkfma(__builtin_amdgcn_cvt_pk_f32_fp8(vA1, false), g2, a01);
  a23 = pkfma(__builtin_amdgcn_cvt_pk_f32_fp8(vA1, true), g2, a23);
  g2.x = gA2; g2.y = gA2;
  a01 = pkfma(__builtin_amdgcn_cvt_pk_f32_fp8(vA2, false), g2, a01);
  a23 = pkfma(__builtin_amdgcn_cvt_pk_f32_fp8(vA2, true), g2, a23);
  g2.x = gA3; g2.y = gA3;
  a01 = pkfma(__builtin_amdgcn_cvt_pk_f32_fp8(vA3, false), g2, a01);
  a23 = pkfma(__builtin_amdgcn_cvt_pk_f32_fp8(vA3, true), g2, a23);
  g2.x = gB0; g2.y = gB0;
  a01 = pkfma(__builtin_amdgcn_cvt_pk_f32_fp8(vB0, false), g2, a01);
  a23 = pkfma(__builtin_amdgcn_cvt_pk_f32_fp8(vB0, true), g2, a23);
  g2.x = gB1; g2.y = gB1;
  a01 = pkfma(__builtin_amdgcn_cvt_pk_f32_fp8(vB1, false), g2, a01);
  a23 = pkfma(__builtin_amdgcn_cvt_pk_f32_fp8(vB1, true), g2, a23);
  g2.x = gB2; g2.y = gB2;
  a01 = pkfma(__builtin_amdgcn_cvt_pk_f32_fp8(vB2, false), g2, a01);
  a23 = pkfma(__builtin_amdgcn_cvt_pk_f32_fp8(vB2, true), g2, a23);
  g2.x = gB3; g2.y = gB3;
  a01 = pkfma(__builtin_amdgcn_cvt_pk_f32_fp8(vB3, false), g2, a01);
  a23 = pkfma(__builtin_amdgcn_cvt_pk_f32_fp8(vB3, true), g2, a23);
}

// TWO adjacent nodes per wave (grid NT/8); epilogue uses all 4 quarter-groups.
// Wave-uniform length-skip avoids clamped iterations for unequal pairs.
// NOTE: flat named registers only — register ARRAYS here spill (round 7).
__global__ __launch_bounds__(256) void k_agg(const int* __restrict__ row_ptr,
                                             const uint2* __restrict__ edges,
                                             const unsigned* __restrict__ cur,
                                             unsigned* __restrict__ nxt,
                                             u64* __restrict__ acc64,
                                             int last) {
  int node0 = (((blockIdx.x << 2) + (threadIdx.x >> 6)) << 1);
  int node1 = node0 + 1;
  unsigned lane = threadIdx.x & 63;
  int d = (int)(lane & 15);
  int g = (int)(lane >> 4);
  int b4 = g << 2;
  int s0 = row_ptr[node0];
  int e0 = row_ptr[node1];      // == s1
  int e1 = row_ptr[node1 + 1];
  int s1 = e0;
  f32x2 x01 = {0.f, 0.f}, x23 = {0.f, 0.f};
  f32x2 y01 = {0.f, 0.f}, y23 = {0.f, 0.f};
  const u64* ep = (const u64*)edges;
  int l0 = e0 - s0, l1 = e1 - s1;
  int len = l0 > l1 ? l0 : l1;
  for (int k = 0; k < len; k += 32) {
    if (k < l0) agg32(ep, cur, s0 + k, e0, d, b4, x01, x23);
    if (k < l1) agg32(ep, cur, s1 + k, e1, d, b4, y01, y23);
  }
  float x0 = x01.x, x1 = x01.y, x2 = x23.x, x3 = x23.y;
  float y0 = y01.x, y1 = y01.y, y2 = y23.x, y3 = y23.y;
  x0 += __shfl_xor(x0, 16, 64); x1 += __shfl_xor(x1, 16, 64);
  x2 += __shfl_xor(x2, 16, 64); x3 += __shfl_xor(x3, 16, 64);
  y0 += __shfl_xor(y0, 16, 64); y1 += __shfl_xor(y1, 16, 64);
  y2 += __shfl_xor(y2, 16, 64); y3 += __shfl_xor(y3, 16, 64);
  x0 += __shfl_xor(x0, 32, 64); x1 += __shfl_xor(x1, 32, 64);
  x2 += __shfl_xor(x2, 32, 64); x3 += __shfl_xor(x3, 32, 64);
  y0 += __shfl_xor(y0, 32, 64); y1 += __shfl_xor(y1, 32, 64);
  y2 += __shfl_xor(y2, 32, 64); y3 += __shfl_xor(y3, 32, 64);
  if (g < 2) {
    int nd = (g == 0) ? node0 : node1;
    float a0 = (g == 0) ? x0 : y0;
    float a1 = (g == 0) ? x1 : y1;
    float a2 = (g == 0) ? x2 : y2;
    float a3 = (g == 0) ? x3 : y3;
    unsigned ro = ((unsigned)nd << 4) + (unsigned)d;
    u64 pv = acc64[ro];
    unsigned lo32 = (unsigned)pv, hi32 = (unsigned)(pv >> 32);
    float z0 = __uint_as_float(lo32 << 16) + a0;
    float z1 = __uint_as_float(lo32 & 0xffff0000u) + a1;
    float z2 = __uint_as_float(hi32 << 16) + a2;
    float z3 = __uint_as_float(hi32 & 0xffff0000u) + a3;
    acc64[ro] = pk4(z0, z1, z2, z3);
  } else if (!last) {
    int nd = (g == 2) ? node0 : node1;
    float a0 = (g == 2) ? x0 : y0;
    float a1 = (g == 2) ? x1 : y1;
    float a2 = (g == 2) ? x2 : y2;
    float a3 = (g == 2) ? x3 : y3;
    unsigned ro = ((unsigned)nd << 4) + (unsigned)d;
    int p = __builtin_amdgcn_cvt_pk_fp8_f32(a0, a1, 0, false);
    p = __builtin_amdgcn_cvt_pk_fp8_f32(a2, a3, p, true);
    nxt[ro] = (unsigned)p;
  }
}

// ---------------- batch pass (MFMA, 128 blocks, big LDS) ----------------
__global__ __launch_bounds__(256) void k_batch(
    const unsigned short* __restrict__ accB,
    const float* __restrict__ user_emb, const float* __restrict__ item_emb,
    const float* __restrict__ eps,
    const float* __restrict__ user_int, const float* __restrict__ item_int,
    const float* __restrict__ lin_w, const float* __restrict__ lin_b,
    const int* __restrict__ users, const int* __restrict__ pos_items,
    const int* __restrict__ neg_items,
    unsigned short* __restrict__ ugen_b, unsigned short* __restrict__ uio_b,
    unsigned short* __restrict__ igen_b, unsigned short* __restrict__ iio_b,
    float* __restrict__ posu, float* __restrict__ posi,
    double* __restrict__ bprp, double* __restrict__ esp) {
  __shared__ __align__(16) unsigned short sUIT[128 * 72];
  __shared__ __align__(16) unsigned short sUI[64 * 136];
  __shared__ __align__(16) unsigned short sP[4][16 * 136];
  __shared__ double red[8];
  int bid = blockIdx.x;
  int lane = threadIdx.x & 63;
  int wid = threadIdx.x >> 6;
  int n = lane & 15, q = lane >> 4;
  int isI = bid >> 6;
  int i0 = ((bid & 63) << 6) + wid * 16;
  const float* intent = isI ? item_int : user_int;
  for (int i = threadIdx.x; i < 8192; i += 256) {
    int dd = i >> 7, kk = i & 127;
    unsigned short v = f2b(intent[i]);
    sUIT[kk * 72 + dd] = v;
    sUI[dd * 136 + kk] = v;
  }
  __syncthreads();
  unsigned short* myP = &sP[wid][0];
  int piN = pos_items[i0 + n];
  int rw = isI ? (NU + piN) : users[i0 + n];
  const unsigned short* arp = accB + (size_t)rw * 64;
  bf16x8 a0 = *(const bf16x8*)(arp + q * 8);
  bf16x8 a1 = *(const bf16x8*)(arp + 32 + q * 8);
  // logits: c[kt](item q*4+r, k=kt*16+n)
  f32x4 c[8];
#pragma unroll
  for (int kt = 0; kt < 8; kt++) {
    const unsigned short* bp = &sUIT[(kt * 16 + n) * 72 + q * 8];
    bf16x8 b0 = *(const bf16x8*)bp;
    bf16x8 b1 = *(const bf16x8*)(bp + 32);
    f32x4 z = {0.f, 0.f, 0.f, 0.f};
    z = __builtin_amdgcn_mfma_f32_16x16x32_bf16(a0, b0, z, 0, 0, 0);
    c[kt] = __builtin_amdgcn_mfma_f32_16x16x32_bf16(a1, b1, z, 0, 0, 0);
  }
  // softmax over k per item
  float mx[4], tot[4];
#pragma unroll
  for (int r = 0; r < 4; r++) {
    float m = c[0][r];
#pragma unroll
    for (int kt = 1; kt < 8; kt++) m = fmaxf(m, c[kt][r]);
#pragma unroll
    for (int o = 1; o < 16; o <<= 1) m = fmaxf(m, __shfl_xor(m, o, 64));
    mx[r] = m;
  }
#pragma unroll
  for (int kt = 0; kt < 8; kt++)
#pragma unroll
    for (int r = 0; r < 4; r++) c[kt][r] = __expf(c[kt][r] - mx[r]);
#pragma unroll
  for (int r = 0; r < 4; r++) {
    float t = 0.f;
#pragma unroll
    for (int kt = 0; kt < 8; kt++) t += c[kt][r];
#pragma unroll
    for (int o = 1; o < 16; o <<= 1) t += __shfl_xor(t, o, 64);
    tot[r] = 1.f / t;
  }
  // P -> LDS (bf16, item-row-major)
#pragma unroll
  for (int kt = 0; kt < 8; kt++)
#pragma unroll
    for (int r = 0; r < 4; r++)
      myP[(q * 4 + r) * 136 + kt * 16 + n] = f2b(c[kt][r] * tot[r]);
  // PV: s[dt](item q*4+r, d=dt*16+n)
  f32x4 s[4];
#pragma unroll
  for (int dt = 0; dt < 4; dt++) s[dt] = (f32x4){0.f, 0.f, 0.f, 0.f};
#pragma unroll
  for (int cc = 0; cc < 4; cc++) {
    bf16x8 pa = *(const bf16x8*)&myP[n * 136 + cc * 32 + q * 8];
#pragma unroll
    for (int dt = 0; dt < 4; dt++) {
      bf16x8 bb = *(const bf16x8*)&sUI[(dt * 16 + n) * 136 + cc * 32 + q * 8];
      s[dt] = __builtin_amdgcn_mfma_f32_16x16x32_bf16(pa, bb, s[dt], 0, 0, 0);
    }
  }
  // io = normalize(s)
  float rin[4];
#pragma unroll
  for (int r = 0; r < 4; r++) {
    float t = 0.f;
#pragma unroll
    for (int dt = 0; dt < 4; dt++) t += s[dt][r] * s[dt][r];
#pragma unroll
    for (int o = 1; o < 16; o <<= 1) t += __shfl_xor(t, o, 64);
    rin[r] = 1.f / sqrtf(t);
  }
  float iov[4][4];
  unsigned short* iob = isI ? iio_b : uio_b;
#pragma unroll
  for (int dt = 0; dt < 4; dt++)
#pragma unroll
    for (int r = 0; r < 4; r++) {
      float v = s[dt][r] * rin[r];
      iov[dt][r] = v;
      iob[(size_t)(i0 + q * 4 + r) * 64 + dt * 16 + n] = f2b(v);
    }
  // sd via K=32 MFMA: A3 = softplus(m[:, :32])
  bf16x8 A3;
#pragma unroll
  for (int j = 0; j < 8; j++) A3[j] = (short)f2b(softplusf(bfe(a0, j)));
  f32x4 sd4[4];
  float lbv[4];
#pragma unroll
  for (int dt = 0; dt < 4; dt++) {
    const float* wp = lin_w + (size_t)(dt * 16 + n) * 32 + q * 8;
    float4 w0 = *(const float4*)wp;
    float4 w1 = *(const float4*)(wp + 4);
    bf16x8 B3;
    B3[0] = (short)f2b(w0.x); B3[1] = (short)f2b(w0.y);
    B3[2] = (short)f2b(w0.z); B3[3] = (short)f2b(w0.w);
    B3[4] = (short)f2b(w1.x); B3[5] = (short)f2b(w1.y);
    B3[6] = (short)f2b(w1.z); B3[7] = (short)f2b(w1.w);
    f32x4 z = {0.f, 0.f, 0.f, 0.f};
    sd4[dt] = __builtin_amdgcn_mfma_f32_16x16x32_bf16(A3, B3, z, 0, 0, 0);
    lbv[dt] = lin_b[dt * 16 + n];
  }
  // m -> C-layout via LDS (raw frags ARE the row data)
  *(bf16x8*)&myP[n * 136 + q * 8] = a0;
  *(bf16x8*)&myP[n * 136 + 32 + q * 8] = a1;
  int rwr[4];
#pragma unroll
  for (int r = 0; r < 4; r++) rwr[r] = __shfl(rw, q * 4 + r, 64);
  float ge[4][4];
#pragma unroll
  for (int dt = 0; dt < 4; dt++)
#pragma unroll
    for (int r = 0; r < 4; r++) {
      float mcv = b2f(myP[(q * 4 + r) * 136 + dt * 16 + n]);
      float ep = eps[(size_t)rwr[r] * 64 + dt * 16 + n];
      float sdf = sd4[dt][r] + lbv[dt] + 1e-8f;
      ge[dt][r] = mcv + ep * sdf;
    }
  float gin[4];
#pragma unroll
  for (int r = 0; r < 4; r++) {
    float t = 0.f;
#pragma unroll
    for (int dt = 0; dt < 4; dt++) t += ge[dt][r] * ge[dt][r];
#pragma unroll
    for (int o = 1; o < 16; o <<= 1) t += __shfl_xor(t, o, 64);
    gin[r] = 1.f / sqrtf(t);
  }
  float pd[4] = {0.f, 0.f, 0.f, 0.f};
  unsigned short* gob = isI ? igen_b : ugen_b;
#pragma unroll
  for (int dt = 0; dt < 4; dt++)
#pragma unroll
    for (int r = 0; r < 4; r++) {
      float go = ge[dt][r] * gin[r];
      gob[(size_t)(i0 + q * 4 + r) * 64 + dt * 16 + n] = f2b(go);
      pd[r] = fmaf(go, iov[dt][r], pd[r]);
    }
  float* posX = isI ? posi : posu;
#pragma unroll
  for (int r = 0; r < 4; r++) {
    float t = pd[r];
#pragma unroll
    for (int o = 1; o < 16; o <<= 1) t += __shfl_xor(t, o, 64);
    if (n == 0) posX[i0 + q * 4 + r] = t;
  }
  // side-specific reductions -> per-block scratch slots (no atomics)
  if (!isI) {
    int niN = neg_items[i0 + n];
    const unsigned short* pp = accB + (size_t)(NU + piN) * 64;
    const unsigned short* np = accB + (size_t)(NU + niN) * 64;
    bf16x8 p0 = *(const bf16x8*)(pp + q * 8);
    bf16x8 p1 = *(const bf16x8*)(pp + 32 + q * 8);
    bf16x8 n0 = *(const bf16x8*)(np + q * 8);
    bf16x8 n1 = *(const bf16x8*)(np + 32 + q * 8);
    float ps = 0.f, ns = 0.f;
#pragma unroll
    for (int j = 0; j < 8; j++) {
      float m0 = bfe(a0, j), m1 = bfe(a1, j);
      ps = fmaf(m0, bfe(p0, j), ps); ps = fmaf(m1, bfe(p1, j), ps);
      ns = fmaf(m0, bfe(n0, j), ns); ns = fmaf(m1, bfe(n1, j), ns);
    }
    ps += __shfl_xor(ps, 16, 64); ps += __shfl_xor(ps, 32, 64);
    ns += __shfl_xor(ns, 16, 64); ns += __shfl_xor(ns, 32, 64);
    float bpr = softplusf(ns - ps);
    const float* uep = user_emb + (size_t)rw * 64 + q * 16;
    float es = 0.f;
#pragma unroll
    for (int j = 0; j < 4; j++) {
      float4 u4 = *(const float4*)(uep + j * 4);
      es += u4.x * u4.x + u4.y * u4.y + u4.z * u4.z + u4.w * u4.w;
    }
    es += __shfl_xor(es, 16, 64); es += __shfl_xor(es, 32, 64);
#pragma unroll
    for (int o = 1; o < 16; o <<= 1) {
      bpr += __shfl_xor(bpr, o, 64);
      es += __shfl_xor(es, o, 64);
    }
    if (lane == 0) { red[wid] = (double)bpr; red[4 + wid] = (double)es; }
    __syncthreads();
    if (threadIdx.x == 0) {
      bprp[bid] = red[0] + red[1] + red[2] + red[3];
      esp[bid] = red[4] + red[5] + red[6] + red[7];
    }
  } else {
    int niN = neg_items[i0 + n];
    const float* pe = item_emb + (size_t)piN * 64 + q * 16;
    const float* ne = item_emb + (size_t)niN * 64 + q * 16;
    float es = 0.f;
#pragma unroll
    for (int j = 0; j < 4; j++) {
      float4 u4 = *(const float4*)(pe + j * 4);
      float4 v4 = *(const float4*)(ne + j * 4);
      es += u4.x * u4.x + u4.y * u4.y + u4.z * u4.z + u4.w * u4.w;
      es += v4.x * v4.x + v4.y * v4.y + v4.z * v4.z + v4.w * v4.w;
    }
    es += __shfl_xor(es, 16, 64); es += __shfl_xor(es, 32, 64);
#pragma unroll
    for (int o = 1; o < 16; o <<= 1) es += __shfl_xor(es, o, 64);
    if (lane == 0) red[wid] = (double)es;
    __syncthreads();
    if (threadIdx.x == 0)
      esp[bid] = red[0] + red[1] + red[2] + red[3];
  }
}

// ---------------- nce + KL + int (merged grid, nce LDS-staged) ----------------
__global__ __launch_bounds__(256) void k_nk(
    const unsigned short* __restrict__ e1u, const unsigned short* __restrict__ e2u,
    const unsigned short* __restrict__ e1i, const unsigned short* __restrict__ e2i,
    float* __restrict__ negu, float* __restrict__ negi,
    const unsigned short* __restrict__ accB,
    const float* __restrict__ lin_w, const float* __restrict__ lin_b,
    const float* __restrict__ user_int, const float* __restrict__ item_int,
    double* __restrict__ klp, double* __restrict__ intp) {
  __shared__ double red[4];
  __shared__ __align__(16) uint4 sE2[2048];  // 256 rows x 128B, swizzled
  int bid = blockIdx.x;
  int lane = threadIdx.x & 63;
  int wid = threadIdx.x >> 6;
  int n = lane & 15, q = lane >> 4;
  if (bid < 2048) {
    // ---- InfoNCE negatives (bf16 MFMA), j split 16-way, LDS-staged ----
    int bx = bid & 63, by = bid >> 6;
    int pr = by >> 4, jq = by & 15;
    const unsigned short* e1 = pr ? e1i : e1u;
    const unsigned short* e2 = pr ? e2i : e2u;
    float* nego = pr ? negi : negu;
    const uint4* e2v = (const uint4*)e2 + (size_t)jq * 2048;
#pragma unroll
    for (int k = 0; k < 8; k++) {
      int i = (int)threadIdx.x + k * 256;
      int row = i >> 3, cch = i & 7;
      sE2[(i & ~7) | (cch ^ (row & 7))] = e2v[i];
    }
    int i0 = bx * 64 + wid * 16;
    const bf16x8* arow = (const bf16x8*)(e1 + (size_t)(i0 + n) * 64 + q * 8);
    bf16x8 a0 = arow[0];
    bf16x8 a1 = arow[4];
    __syncthreads();
    f32x4 accv = {0.f, 0.f, 0.f, 0.f};
    int sw = n & 7;
    for (int jt = 0; jt < 16; jt += 2) {
      int r0 = jt * 16 + n;
      const uint4* base0 = &sE2[r0 * 8];
      const uint4* base1 = &sE2[(r0 + 16) * 8];
      bf16x8 b0 = *(const bf16x8*)&base0[q ^ sw];
      bf16x8 b1 = *(const bf16x8*)&base0[(q + 4) ^ sw];
      bf16x8 b2 = *(const bf16x8*)&base1[q ^ sw];
      bf16x8 b3 = *(const bf16x8*)&base1[(q + 4) ^ sw];
      f32x4 c = {0.f, 0.f, 0.f, 0.f};
      f32x4 c2 = {0.f, 0.f, 0.f, 0.f};
      c = __builtin_amdgcn_mfma_f32_16x16x32_bf16(a0, b0, c, 0, 0, 0);
      c = __builtin_amdgcn_mfma_f32_16x16x32_bf16(a1, b1, c, 0, 0, 0);
      c2 = __builtin_amdgcn_mfma_f32_16x16x32_bf16(a0, b2, c2, 0, 0, 0);
      c2 = __builtin_amdgcn_mfma_f32_16x16x32_bf16(a1, b3, c2, 0, 0, 0);
#pragma unroll
      for (int r = 0; r < 4; r++)
        accv[r] += __expf(5.0f * c[r]) + __expf(5.0f * c2[r]);
    }
#pragma unroll
    for (int o = 1; o < 16; o <<= 1) {
#pragma unroll
      for (int r = 0; r < 4; r++) accv[r] += __shfl_xor(accv[r], o, 64);
    }
    if (n == 0) {
#pragma unroll
      for (int r = 0; r < 4; r++) atomicAdd(&nego[i0 + q * 4 + r], accv[r]);
    }
  } else if (bid < 2048 + KLB) {
    // ---- KL branch (MFMA over bf16 acc; partial->slot; 16B loads) ----
    bf16x8 B0, B1, B2, B3;
    float lb0, lb1, lb2, lb3;
    {
      const float* w0 = lin_w + (0 * 16 + n) * 32 + q * 8;
      const float* w1 = lin_w + (1 * 16 + n) * 32 + q * 8;
      const float* w2 = lin_w + (2 * 16 + n) * 32 + q * 8;
      const float* w3 = lin_w + (3 * 16 + n) * 32 + q * 8;
#pragma unroll
      for (int j = 0; j < 8; j++) {
        B0[j] = (short)f2b(w0[j]);
        B1[j] = (short)f2b(w1[j]);
        B2[j] = (short)f2b(w2[j]);
        B3[j] = (short)f2b(w3[j]);
      }
      lb0 = lin_b[0 * 16 + n] + 1e-8f;
      lb1 = lin_b[1 * 16 + n] + 1e-8f;
      lb2 = lin_b[2 * 16 + n] + 1e-8f;
      lb3 = lin_b[3 * 16 + n] + 1e-8f;
    }
    const int TI = NT / 16;
    int w0id = (bid - 2048) * 4 + wid;
    int nwv = KLB * 4;
    double dsum = 0.0;
    for (int tile = w0id; tile < TI; tile += nwv) {
      const uint4* rp = (const uint4*)(accB + (size_t)(tile * 16 + n) * 64 + q * 8);
      uint4 A = rp[0];
      uint4 C = rp[4];   // +32 dims = +64B = +4 uint4
      u64 A0 = ((u64)A.y << 32) | A.x;
      u64 A1 = ((u64)A.w << 32) | A.z;
      u64 C0 = ((u64)C.y << 32) | C.x;
      u64 C1 = ((u64)C.w << 32) | C.z;
      float av[8], bv[8];
      unp4(A0, av); unp4(A1, av + 4);
      unp4(C0, bv); unp4(C1, bv + 4);
      float msum = 0.f;
#pragma unroll
      for (int j = 0; j < 8; j++) msum += av[j] * av[j] + bv[j] * bv[j];
      bf16x8 Af;
#pragma unroll
      for (int j = 0; j < 8; j++) Af[j] = (short)f2b(softplusf(av[j]));
      f32x4 z = {0.f, 0.f, 0.f, 0.f};
      f32x4 c0 = __builtin_amdgcn_mfma_f32_16x16x32_bf16(Af, B0, z, 0, 0, 0);
      f32x4 c1 = __builtin_amdgcn_mfma_f32_16x16x32_bf16(Af, B1, z, 0, 0, 0);
      f32x4 c2 = __builtin_amdgcn_mfma_f32_16x16x32_bf16(Af, B2, z, 0, 0, 0);
      f32x4 c3 = __builtin_amdgcn_mfma_f32_16x16x32_bf16(Af, B3, z, 0, 0, 0);
      float ksum = 0.f;
#pragma unroll
      for (int r = 0; r < 4; r++) {
        float s0 = c0[r] + lb0, s1 = c1[r] + lb1, s2 = c2[r] + lb2, s3 = c3[r] + lb3;
        ksum += -0.5f * (1.f + 2.f * s0 - __expf(2.f * s0));
        ksum += -0.5f * (1.f + 2.f * s1 - __expf(2.f * s1));
        ksum += -0.5f * (1.f + 2.f * s2 - __expf(2.f * s2));
        ksum += -0.5f * (1.f + 2.f * s3 - __expf(2.f * s3));
      }
      dsum += (double)wsum(ksum + 0.5f * msum);
    }
    if (lane == 0) red[wid] = dsum;
    __syncthreads();
    if (threadIdx.x == 0)
      klp[bid - 2048] = red[0] + red[1] + red[2] + red[3];
  } else {
    // ---- int_loss block ----
    float s = 0.f;
    for (int i = threadIdx.x; i < 64 * 128; i += 256) {
      float a = user_int[i], b = item_int[i];
      s = fmaf(a, a, s);
      s = fmaf(b, b, s);
    }
    s = wsum(s);
    if (lane == 0) red[wid] = (double)s;
    __syncthreads();
    if (threadIdx.x == 0)
      intp[0] = red[0] + red[1] + red[2] + red[3];
  }
}

// final combine: partial-array sums + nce log-sum + output assembly (1 block)
__global__ __launch_bounds__(256) void k_out(
    const float* __restrict__ posu, const float* __restrict__ posi,
    const float* __restrict__ negu, const float* __restrict__ negi,
    const double* __restrict__ bprp, const double* __restrict__ esp,
    const double* __restrict__ klp, const double* __restrict__ intp,
    float* __restrict__ out) {
  __shared__ double redd[16];
  int tid = threadIdx.x;
  int lane = tid & 63, wid = tid >> 6;
  double cl = 0.0;
  for (int i = tid; i < 2 * BB; i += 256) {
    int pr = i >> 12, idx = i & (BB - 1);
    float ng = pr ? negi[idx] : negu[idx];
    float dt = pr ? posi[idx] : posu[idx];
    float pos = expf(5.0f * dt);
    cl += (double)(-logf(pos / (ng + 1e-8f) + 1e-8f));
  }
  double kl = 0.0;
  for (int i = tid; i < KLB; i += 256) kl += klp[i];
  double bpr = (tid < 64) ? bprp[tid] : 0.0;
  double es = (tid < 128) ? esp[tid] : 0.0;
#pragma unroll
  for (int o = 32; o > 0; o >>= 1) {
    cl += __shfl_xor(cl, o, 64);
    kl += __shfl_xor(kl, o, 64);
    bpr += __shfl_xor(bpr, o, 64);
    es += __shfl_xor(es, o, 64);
  }
  if (lane == 0) {
    redd[wid] = cl; redd[4 + wid] = kl;
    redd[8 + wid] = bpr; redd[12 + wid] = es;
  }
  __syncthreads();
  if (tid == 0) {
    double cls = redd[0] + redd[1] + redd[2] + redd[3];
    double kls = redd[4] + redd[5] + redd[6] + redd[7];
    double bprs = redd[8] + redd[9] + redd[10] + redd[11];
    double ess = redd[12] + redd[13] + redd[14] + redd[15];
    out[0] = (float)(bprs / (double)BB + 0.01 * kls / (double)NT);
    out[1] = (float)(0.1 * cls / (double)BB);
    out[2] = (float)(1e-5 * ess);
    out[3] = (float)(1e-5 * intp[0]);
  }
}

extern "C" void kernel_launch(void* const* d_in, const int* in_sizes, int n_in,
                              void* d_out, int out_size, void* d_ws, size_t ws_size,
                              hipStream_t stream) {
  const float* user_emb = (const float*)d_in[0];
  const float* item_emb = (const float*)d_in[1];
  const float* user_int = (const float*)d_in[2];
  const float* item_int = (const float*)d_in[3];
  const float* lin_w = (const float*)d_in[4];
  const float* lin_b = (const float*)d_in[5];
  const float* eps = (const float*)d_in[6];
  const int* h_list = (const int*)d_in[7];
  const int* t_list = (const int*)d_in[8];
  const int* users = (const int*)d_in[9];
  const int* pos_items = (const int*)d_in[10];
  const int* neg_items = (const int*)d_in[11];
  float* out = (float*)d_out;
  const int E = in_sizes[7];

  char* ws = (char*)d_ws;
  size_t off = 0;
  auto take = [&](size_t bytes) -> char* {
    char* p = ws + off;
    off = (off + bytes + 255) & ~(size_t)255;
    return p;
  };
  int* row_ptr = (int*)take((size_t)(NT + 1) * 4);
  float* d_inv = (float*)take((size_t)NT * 4);
  int* rloc_g = (int*)take((size_t)NT * 4);
  int* cnt_chunk = (int*)take((size_t)NBUCK * NCH * 1024 * 4);
  int* gcur = (int*)take(NBUCK * 4);
  int* btot = (int*)take(NBUCK * 4);
  uint2* edges = (uint2*)take((size_t)E * 8);
  unsigned* bufA = (unsigned*)take((size_t)NT * 16 * 4);  // fp8 rows (16 dwords)
  unsigned* bufB = (unsigned*)take((size_t)NT * 16 * 4);
  // accB (bf16 rows, 19.2MB) shares a region with part (28.9MB): part's last
  // read is k_fill2; accB is first written in k_init (which runs after).
  unsigned short* accB = (unsigned short*)take((size_t)NBUCK * BCAP * 8);
  unsigned short* ugen_b = (unsigned short*)take((size_t)BB * 64 * 2);
  unsigned short* igen_b = (unsigned short*)take((size_t)BB * 64 * 2);
  unsigned short* uio_b = (unsigned short*)take((size_t)BB * 64 * 2);
  unsigned short* iio_b = (unsigned short*)take((size_t)BB * 64 * 2);
  float* posu = (float*)take((size_t)BB * 4);
  float* posi = (float*)take((size_t)BB * 4);
  float* negu = (float*)take((size_t)BB * 4);
  float* negi = (float*)take((size_t)BB * 4);
  double* klp = (double*)take((size_t)KLB * 8);
  double* bprp = (double*)take(64 * 8);
  double* esp = (double*)take(128 * 8);
  double* intp = (double*)take(8);
  if (off > ws_size) return;
  uint2* part = (uint2*)accB;
  u64* acc64 = (u64*)accB;

  k_zero<<<1, 256, 0, stream>>>(gcur, negu, negi);

  int gridP = (E + 4095) / 4096;
  k_part<<<gridP, 256, 0, stream>>>(h_list, t_list, gcur, part, E);
  k_count2<<<dim3(NBUCK, NCH), 256, 0, stream>>>(part, gcur, cnt_chunk);
  k_node<<<NBUCK, 256, 0, stream>>>(cnt_chunk, rloc_g, d_inv, btot);
  k_fill2<<<dim3(NBUCK, NCH), 256, 0, stream>>>(part, gcur, cnt_chunk, rloc_g,
                                                btot, d_inv, edges, row_ptr);

  int nU4 = NU * 16, nTot4 = NT * 16;
  k_init<<<(nTot4 + 255) / 256, 256, 0, stream>>>((const float4*)user_emb,
                                                  (const float4*)item_emb, bufA,
                                                  acc64, nU4, nTot4);
  int gridAgg = NT / 8;
  k_agg<<<gridAgg, 256, 0, stream>>>(row_ptr, edges, bufA, bufB, acc64, 0);
  k_agg<<<gridAgg, 256, 0, stream>>>(row_ptr, edges, bufB, bufA, acc64, 0);
  k_agg<<<gridAgg, 256, 0, stream>>>(row_ptr, edges, bufA, bufB, acc64, 1);

  k_batch<<<128, 256, 0, stream>>>(accB, user_emb, item_emb, eps,
                                   user_int, item_int, lin_w, lin_b,
                                   users, pos_items, neg_items,
                                   ugen_b, uio_b, igen_b, iio_b,
                                   posu, posi, bprp, esp);
  k_nk<<<2048 + KLB + 1, 256, 0, stream>>>(ugen_b, uio_b, igen_b, iio_b,
                                           negu, negi, accB, lin_w, lin_b,
                                           user_int, item_int, klp, intp);
  k_out<<<1, 256, 0, stream>>>(posu, posi, negu, negi, bprp, esp, klp, intp,
                               out);
}